// Round 9
// baseline (55.057 us; speedup 1.0000x reference)
//
// Fused 3-bit dequant GEMM: C[64,11008] = A[64,4096] @ ((q-4) * s[group])
// R9: fold cvtA into the main kernel (one fewer dispatch + gap, ~3-4us).
// Per step each wave stages 3 uniform global_load_lds: 2x q dwordx4 (rotation
// swizzle, as R6) + 1x A f32 dwordx4 (slice [64 rows][32 k] = 8KB from
// L2-resident A; slot-rotation swizzle (slot+row&7)&7 via pre-rotated global
// source -> uniform 8-slot bank coverage on the b128 fragment reads).
// Fragments built in-register: 2x ds_read_b128 + 4 packs per mt.
// LDS 4x(16+8)KB = 96KB -> 1 block/CU (OK: BW-bound, 2 staged tiles in
// flight via counted vmcnt(6/3/0); Little's law needs ~11KB/CU, we hold 48).
// Rest is exact R6 (best: 44.1us): SB=8, NBUF=4, compute-then-stage,
// raw s_barrier + sched_barrier(0), bf16 partials + reduce kernel.
// R7 lesson kept: no agent-scope fences in hot kernels (L2 flush on gfx950).
// Predicted total ~40us; FETCH ~182MB (if ~270MB -> q thrashes L2, add NT).

#include <hip/hip_runtime.h>

#define K_ 4096
#define N_ 11008
#define M_ 64
#define SB 8                    // k-split factor
#define CB 86                   // column chunks of BN
#define BK 32                   // k rows per tile
#define BN 128                  // columns per block
#define KBAND (K_ / SB)         // 512
#define NSTEP (KBAND / BK)      // 16
#define NBUF 4

typedef __attribute__((ext_vector_type(8))) short bf16x8;
typedef __attribute__((ext_vector_type(4))) float f32x4;
typedef __attribute__((ext_vector_type(4))) unsigned uint4v;
typedef __attribute__((ext_vector_type(4))) float float4v;
typedef __attribute__((ext_vector_type(4))) unsigned short ushort4v;

static __device__ __forceinline__ unsigned rne_bits(float f) {
  unsigned u = __builtin_bit_cast(unsigned, f);
  return u + 0x7fffu + ((u >> 16) & 1u);   // bf16 in bits [31:16], RNE
}
static __device__ __forceinline__ unsigned pack_bf16(float lo, float hi) {
  return (rne_bits(hi) & 0xffff0000u) | (rne_bits(lo) >> 16);
}
static __device__ __forceinline__ unsigned short bf16_1(float f) {
  return (unsigned short)(rne_bits(f) >> 16);
}
static __device__ __forceinline__ float bf16_to_f32(unsigned short u) {
  return __builtin_bit_cast(float, (unsigned)u << 16);
}

// ---------------- pipelined hot path (requires P in d_ws) ------------------
__global__ __launch_bounds__(512, 2) void dq_gemm_pipe(
    const int* __restrict__ q, const float* __restrict__ s,
    const float* __restrict__ A, unsigned short* __restrict__ P) {
  __shared__ int   qtile[NBUF][BK * BN];   // 4 x 16KB
  __shared__ float atile[NBUF][64 * 32];   // 4 x 8KB  (A slice, swizzled)

  const int tid = threadIdx.x;
  const int l   = tid & 63;
  const int w   = tid >> 6;           // wave 0..7 (owns 16 columns)
  const int fr  = l & 15;
  const int lg  = l >> 4;
  const int cb  = blockIdx.x % CB;
  const int sb  = blockIdx.x / CB;
  const int n0  = cb * BN;
  const int k0  = sb * KBAND;
  const int cw  = w * 16;

  // --- scales preload FIRST (oldest vmem; retired by the first wait) ---
  float scv[NSTEP / 2];
  #pragma unroll
  for (int g = 0; g < NSTEP / 2; ++g)
    scv[g] = s[(size_t)((k0 >> 6) + g) * N_ + n0 + cw + fr];

  f32x4 acc[4] = {f32x4{0,0,0,0}, f32x4{0,0,0,0}, f32x4{0,0,0,0}, f32x4{0,0,0,0}};

  // stage = exactly 3 uniform loads/wave:
  //  2x q dwordx4: rotation swizzle via pre-rotated per-lane global source
  //  1x A dwordx4: wave w covers A rows 8w..8w+7, 32 k (f32); slot-rotation
  //     swizzle (slot + row&7)&7 pre-applied on the global source.
  auto stage = [&](int buf, int kst) {
    #pragma unroll
    for (int i = 0; i < 2; ++i) {
      const int rbase = w * 4 + i * 2;               // wave-uniform row pair
      const int row   = rbase + (l >> 5);
      const int rot   = ((row >> 3) & 3) * 8;
      const int c4    = (4 * l) & 127;
      const int src   = (c4 - rot) & 127;
      const int* gp   = q + (size_t)(kst + row) * N_ + n0 + src;
      __builtin_amdgcn_global_load_lds(
          (const __attribute__((address_space(1))) unsigned*)gp,
          (__attribute__((address_space(3))) unsigned*)&qtile[buf][rbase * BN],
          16, 0, 0);
    }
    {
      const int arow   = w * 8 + (l >> 3);           // A row this lane fills
      const int slot_g = ((l & 7) - (l >> 3)) & 7;   // pre-rotated src slot
      const float* ap  = A + (size_t)arow * K_ + kst + slot_g * 4;
      __builtin_amdgcn_global_load_lds(
          (const __attribute__((address_space(1))) unsigned*)ap,
          (__attribute__((address_space(3))) unsigned*)&atile[buf][w * 256],
          16, 0, 0);
    }
  };

  auto compute = [&](int buf, float sc) {
    // A fragments from swizzled LDS: row = mt*16+fr, k-slots 2lg, 2lg+1
    bf16x8 af[4];
    #pragma unroll
    for (int mt = 0; mt < 4; ++mt) {
      const int arow = mt * 16 + fr;
      const int s0   = (lg * 2 + (fr & 7)) & 7;
      const int s1   = (lg * 2 + 1 + (fr & 7)) & 7;
      float4v va = *reinterpret_cast<const float4v*>(&atile[buf][arow * 32 + s0 * 4]);
      float4v vb = *reinterpret_cast<const float4v*>(&atile[buf][arow * 32 + s1 * 4]);
      uint4v b = { pack_bf16(va[0], va[1]), pack_bf16(va[2], va[3]),
                   pack_bf16(vb[0], vb[1]), pack_bf16(vb[2], vb[3]) };
      af[mt] = __builtin_bit_cast(bf16x8, b);
    }
    const float sn = -4.0f * sc;                     // fma(q, s, -4s)
    const int rot = 8 * lg;
    const int ci  = (cw + fr + rot) & 127;
    unsigned pk[4];
    #pragma unroll
    for (int p = 0; p < 4; ++p) {
      const int r0 = 8 * lg + 2 * p;
      const int c0 = qtile[buf][r0 * BN + ci];
      const int c1 = qtile[buf][(r0 + 1) * BN + ci];
      pk[p] = pack_bf16(fmaf((float)c0, sc, sn), fmaf((float)c1, sc, sn));
    }
    uint4v bv = {pk[0], pk[1], pk[2], pk[3]};
    const bf16x8 bfrag = __builtin_bit_cast(bf16x8, bv);
    #pragma unroll
    for (int mt = 0; mt < 4; ++mt)
      acc[mt] = __builtin_amdgcn_mfma_f32_16x16x32_bf16(af[mt], bfrag, acc[mt],
                                                        0, 0, 0);
  };

  // ---- prologue: 3 tiles in flight (9 stage loads after 8 scv loads) ----
  stage(0, k0);
  stage(1, k0 + BK);
  stage(2, k0 + 2 * BK);

  // ---- steady state: vmcnt(6) retires scv + tile st, keeps 2 tiles in
  // flight; compute-then-stage (R6 order) ----
  #pragma unroll
  for (int st = 0; st < NSTEP - 2; ++st) {
    asm volatile("s_waitcnt vmcnt(6)" ::: "memory");
    __builtin_amdgcn_s_barrier();
    __builtin_amdgcn_sched_barrier(0);   // pin ds_reads below the barrier
    compute(st & 3, scv[st >> 1]);
    if (st + 3 < NSTEP) stage((st + 3) & 3, k0 + (st + 3) * BK);
  }
  // ---- tail: two peeled steps ----
  asm volatile("s_waitcnt vmcnt(3)" ::: "memory");
  __builtin_amdgcn_s_barrier();
  __builtin_amdgcn_sched_barrier(0);
  compute((NSTEP - 2) & 3, scv[(NSTEP - 2) >> 1]);

  asm volatile("s_waitcnt vmcnt(0)" ::: "memory");
  __builtin_amdgcn_s_barrier();
  __builtin_amdgcn_sched_barrier(0);
  compute((NSTEP - 1) & 3, scv[(NSTEP - 1) >> 1]);

  // ---- epilogue: D row = mt*16 + 4*lg + j, col = cw + fr ----
  unsigned short* Pb = P + (size_t)(cb * SB + sb) * M_ * BN;
  #pragma unroll
  for (int mt = 0; mt < 4; ++mt)
    #pragma unroll
    for (int j = 0; j < 4; ++j)
      Pb[(mt * 16 + 4 * lg + j) * BN + cw + fr] = bf16_1(acc[mt][j]);
}

// Sum SB bf16 partials -> f32 out. 688 blocks x 256 thr, 1 ushort4/thread.
__global__ __launch_bounds__(256) void reduce_kernel(
    const unsigned short* __restrict__ P, float* __restrict__ out) {
  const int flat = blockIdx.x * 256 + threadIdx.x;  // 0 .. 176127
  const int cb = flat >> 11;                        // 2048 groups per chunk
  const int r  = flat & 2047;
  const int m  = r >> 5;                            // row (BN/4 = 32 grp/row)
  const int cq = (r & 31) * 4;
  const unsigned short* p = P + ((size_t)cb * SB * M_ + m) * BN + cq;
  float s0 = 0.f, s1 = 0.f, s2 = 0.f, s3 = 0.f;
  #pragma unroll
  for (int sb = 0; sb < SB; ++sb) {
    ushort4v v = *reinterpret_cast<const ushort4v*>(p + (size_t)sb * M_ * BN);
    s0 += bf16_to_f32(v[0]);
    s1 += bf16_to_f32(v[1]);
    s2 += bf16_to_f32(v[2]);
    s3 += bf16_to_f32(v[3]);
  }
  float4v o = {s0, s1, s2, s3};
  *reinterpret_cast<float4v*>(out + (size_t)m * N_ + cb * BN + cq) = o;
}

// ---------------- fallback (ws too small): 2-buf, atomic epilogue ----------
__global__ __launch_bounds__(512, 8) void dq_gemm_basic(
    const int* __restrict__ q, const float* __restrict__ s,
    const float* __restrict__ Af, float* __restrict__ out) {
  __shared__ int tile[2][BK * BN];

  const int tid = threadIdx.x;
  const int l   = tid & 63;
  const int w   = tid >> 6;
  const int fr  = l & 15;
  const int lg  = l >> 4;
  const int cb  = blockIdx.x % CB;
  const int sb  = blockIdx.x / CB;
  const int n0  = cb * BN;
  const int k0  = sb * KBAND;
  const int cw  = w * 16;

  f32x4 acc[4] = {f32x4{0,0,0,0}, f32x4{0,0,0,0}, f32x4{0,0,0,0}, f32x4{0,0,0,0}};

  auto stage = [&](int buf, int kst) {
    #pragma unroll
    for (int i = 0; i < 2; ++i) {
      const int rbase = w * 4 + i * 2;
      const int row   = rbase + (l >> 5);
      const int rot   = ((row >> 3) & 3) * 8;
      const int c4    = (4 * l) & 127;
      const int src   = (c4 - rot) & 127;
      const int* gp   = q + (size_t)(kst + row) * N_ + n0 + src;
      __builtin_amdgcn_global_load_lds(
          (const __attribute__((address_space(1))) unsigned*)gp,
          (__attribute__((address_space(3))) unsigned*)&tile[buf][rbase * BN],
          16, 0, 0);
    }
  };

  auto compute = [&](int buf, int kst) {
    const float sc = s[(size_t)(kst >> 6) * N_ + n0 + cw + fr];
    bf16x8 af[4];
    #pragma unroll
    for (int mt = 0; mt < 4; ++mt) {
      const float* ap = Af + (size_t)(mt * 16 + fr) * K_ + kst + 8 * lg;
      float4v v0 = *reinterpret_cast<const float4v*>(ap);
      float4v v1 = *reinterpret_cast<const float4v*>(ap + 4);
      uint4v b = { pack_bf16(v0[0], v0[1]), pack_bf16(v0[2], v0[3]),
                   pack_bf16(v1[0], v1[1]), pack_bf16(v1[2], v1[3]) };
      af[mt] = __builtin_bit_cast(bf16x8, b);
    }
    const float sn = -4.0f * sc;
    const int rot = 8 * lg;
    const int ci  = (cw + fr + rot) & 127;
    unsigned pk[4];
    #pragma unroll
    for (int p = 0; p < 4; ++p) {
      const int r0 = 8 * lg + 2 * p;
      const int c0 = tile[buf][r0 * BN + ci];
      const int c1 = tile[buf][(r0 + 1) * BN + ci];
      pk[p] = pack_bf16(fmaf((float)c0, sc, sn), fmaf((float)c1, sc, sn));
    }
    uint4v bv = {pk[0], pk[1], pk[2], pk[3]};
    const bf16x8 bfrag = __builtin_bit_cast(bf16x8, bv);
    #pragma unroll
    for (int mt = 0; mt < 4; ++mt)
      acc[mt] = __builtin_amdgcn_mfma_f32_16x16x32_bf16(af[mt], bfrag, acc[mt],
                                                        0, 0, 0);
  };

  stage(0, k0);
  __syncthreads();
  for (int st = 0; st < NSTEP; ++st) {
    const int kst = k0 + st * BK;
    if (st + 1 < NSTEP) stage((st + 1) & 1, kst + BK);
    compute(st & 1, kst);
    __syncthreads();
  }

  #pragma unroll
  for (int mt = 0; mt < 4; ++mt)
    #pragma unroll
    for (int j = 0; j < 4; ++j)
      atomicAdd(out + (size_t)(mt * 16 + 4 * lg + j) * N_ + n0 + cw + fr,
                acc[mt][j]);
}

extern "C" void kernel_launch(void* const* d_in, const int* in_sizes, int n_in,
                              void* d_out, int out_size, void* d_ws, size_t ws_size,
                              hipStream_t stream) {
  const float* A = (const float*)d_in[0];
  const int*   q = (const int*)d_in[1];
  const float* s = (const float*)d_in[2];
  float* out = (float*)d_out;

  const size_t pBytes = (size_t)CB * SB * M_ * BN * sizeof(unsigned short);

  if (ws_size >= pBytes) {
    unsigned short* P = (unsigned short*)d_ws;
    hipLaunchKernelGGL(dq_gemm_pipe, dim3(CB * SB), dim3(512), 0, stream,
                       q, s, A, P);
    hipLaunchKernelGGL(reduce_kernel, dim3(688), dim3(256), 0, stream, P, out);
  } else {
    hipMemsetAsync(d_out, 0, (size_t)M_ * N_ * sizeof(float), stream);
    hipLaunchKernelGGL(dq_gemm_basic, dim3(CB * SB), dim3(512), 0, stream,
                       q, s, A, out);
  }
}

// Round 10
// 52.419 us; speedup vs baseline: 1.0503x; 1.0503x over previous
//
// Fused 3-bit dequant GEMM: C[64,11008] = A[64,4096] @ ((q-4) * s[group])
// R10: exact-R6 main loop (best: 44.1us) + direct f32 atomicAdd epilogue.
// Drops the P partial buffer (22.6MB round-trip) and the reduce dispatch;
// out is zeroed by hipMemsetAsync (graph-safe). No fences (R7 lesson: agent
// fences flush non-coherent per-XCD L2s -> 6x collapse); atomicAdd on global
// f32 is device-scope by default (m20) and needs no fence.
// R9 lesson kept: latency hiding here is block-level TLP — keep 64KB LDS,
// 2 blocks/CU, 16 waves/CU; cvtA stays a separate tiny dispatch.
// Main: NBUF=4 circular LDS pipeline, counted vmcnt(8/4/0), raw s_barrier +
// sched_barrier(0), 4 uniform loads/stage/wave (2 q-dwordx4 + 2 A-frag),
// rotation swizzle (2-way bank = free), Apf fragment-order A.
// Predicted total 38-41us (abort: >44 -> revert R6, declare roofline).

#include <hip/hip_runtime.h>

#define K_ 4096
#define N_ 11008
#define M_ 64
#define SB 8                    // k-split factor
#define CB 86                   // column chunks of BN
#define BK 32                   // k rows per tile
#define BN 128                  // columns per block
#define KBAND (K_ / SB)         // 512
#define NSTEP (KBAND / BK)      // 16
#define NBUF 4

typedef __attribute__((ext_vector_type(8))) short bf16x8;
typedef __attribute__((ext_vector_type(4))) float f32x4;
typedef __attribute__((ext_vector_type(4))) unsigned uint4v;
typedef __attribute__((ext_vector_type(4))) float float4v;

static __device__ __forceinline__ unsigned rne_bits(float f) {
  unsigned u = __builtin_bit_cast(unsigned, f);
  return u + 0x7fffu + ((u >> 16) & 1u);   // bf16 in bits [31:16], RNE
}
static __device__ __forceinline__ unsigned pack_bf16(float lo, float hi) {
  return (rne_bits(hi) & 0xffff0000u) | (rne_bits(lo) >> 16);
}

// A (64x4096 f32) -> Apf in MFMA fragment order: Apf[kt][mt][lane] = 8 bf16
// (4 uints). kt=k/32 (128), mt=row-tile (4), lane=64. 512KB total.
__global__ __launch_bounds__(256) void cvtA_frag_kernel(
    const float* __restrict__ A, unsigned* __restrict__ Apf) {
  const int kt = blockIdx.x;          // 0..127
  const int mt = threadIdx.x >> 6;    // 0..3
  const int l  = threadIdx.x & 63;
  const int row = mt * 16 + (l & 15);
  const int kk  = kt * 32 + (l >> 4) * 8;
  const float* ap = A + (size_t)row * K_ + kk;
  uint4v b = { pack_bf16(ap[0], ap[1]), pack_bf16(ap[2], ap[3]),
               pack_bf16(ap[4], ap[5]), pack_bf16(ap[6], ap[7]) };
  *reinterpret_cast<uint4v*>(Apf + ((size_t)(kt * 4 + mt) * 64 + l) * 4) = b;
}

// ---------------- pipelined hot path (requires Apf in d_ws) ----------------
__global__ __launch_bounds__(512, 4) void dq_gemm_pipe(
    const int* __restrict__ q, const float* __restrict__ s,
    const unsigned* __restrict__ Apf, float* __restrict__ out) {
  __shared__ int qtile[NBUF][BK * BN];   // 4 x 16KB
  __shared__ int atile[NBUF][1024];      // 4 x 4KB  (Apf[kt] linear copy)

  const int tid = threadIdx.x;
  const int l   = tid & 63;
  const int w   = tid >> 6;           // wave 0..7 (owns 16 columns)
  const int fr  = l & 15;
  const int lg  = l >> 4;
  const int cb  = blockIdx.x % CB;
  const int sb  = blockIdx.x / CB;
  const int n0  = cb * BN;
  const int k0  = sb * KBAND;
  const int cw  = w * 16;

  // --- scales preload FIRST (oldest vmem; retired by the first wait) ---
  float scv[NSTEP / 2];
  #pragma unroll
  for (int g = 0; g < NSTEP / 2; ++g)
    scv[g] = s[(size_t)((k0 >> 6) + g) * N_ + n0 + cw + fr];

  f32x4 acc[4] = {f32x4{0,0,0,0}, f32x4{0,0,0,0}, f32x4{0,0,0,0}, f32x4{0,0,0,0}};

  // stage = exactly 4 uniform loads/wave: 2x q dwordx4 (rotation swizzle via
  // pre-rotated per-lane global source; LDS dest linear) + 2x A-frag dword.
  auto stage = [&](int buf, int kst) {
    #pragma unroll
    for (int i = 0; i < 2; ++i) {
      const int rbase = w * 4 + i * 2;               // wave-uniform row pair
      const int row   = rbase + (l >> 5);
      const int rot   = ((row >> 3) & 3) * 8;
      const int c4    = (4 * l) & 127;
      const int src   = (c4 - rot) & 127;
      const int* gp   = q + (size_t)(kst + row) * N_ + n0 + src;
      __builtin_amdgcn_global_load_lds(
          (const __attribute__((address_space(1))) unsigned*)gp,
          (__attribute__((address_space(3))) unsigned*)&qtile[buf][rbase * BN],
          16, 0, 0);
    }
    const unsigned* ab = Apf + (size_t)(kst >> 5) * 1024 + w * 128;
    #pragma unroll
    for (int i = 0; i < 2; ++i) {
      __builtin_amdgcn_global_load_lds(
          (const __attribute__((address_space(1))) unsigned*)(ab + i * 64 + l),
          (__attribute__((address_space(3))) unsigned*)&atile[buf][w * 128 + i * 64],
          4, 0, 0);
    }
  };

  auto compute = [&](int buf, float sc) {
    bf16x8 af[4];
    #pragma unroll
    for (int mt = 0; mt < 4; ++mt)
      af[mt] = *reinterpret_cast<const bf16x8*>(&atile[buf][mt * 256 + l * 4]);
    const float sn = -4.0f * sc;                     // fma(q, s, -4s)
    const int rot = 8 * lg;
    const int ci  = (cw + fr + rot) & 127;
    unsigned pk[4];
    #pragma unroll
    for (int p = 0; p < 4; ++p) {
      const int r0 = 8 * lg + 2 * p;
      const int c0 = qtile[buf][r0 * BN + ci];
      const int c1 = qtile[buf][(r0 + 1) * BN + ci];
      pk[p] = pack_bf16(fmaf((float)c0, sc, sn), fmaf((float)c1, sc, sn));
    }
    uint4v bv = {pk[0], pk[1], pk[2], pk[3]};
    const bf16x8 bfrag = __builtin_bit_cast(bf16x8, bv);
    #pragma unroll
    for (int mt = 0; mt < 4; ++mt)
      acc[mt] = __builtin_amdgcn_mfma_f32_16x16x32_bf16(af[mt], bfrag, acc[mt],
                                                        0, 0, 0);
  };

  // ---- prologue: 3 tiles in flight (12 loads after 8 scv loads) ----
  stage(0, k0);
  stage(1, k0 + BK);
  stage(2, k0 + 2 * BK);

  // ---- steady state: counted wait keeps >=2 tiles in flight ----
  #pragma unroll
  for (int st = 0; st < NSTEP - 2; ++st) {
    asm volatile("s_waitcnt vmcnt(8)" ::: "memory");
    __builtin_amdgcn_s_barrier();
    __builtin_amdgcn_sched_barrier(0);   // pin ds_reads below the barrier
    compute(st & 3, scv[st >> 1]);
    if (st + 3 < NSTEP) stage((st + 3) & 3, k0 + (st + 3) * BK);
  }
  // ---- tail: two peeled steps ----
  asm volatile("s_waitcnt vmcnt(4)" ::: "memory");
  __builtin_amdgcn_s_barrier();
  __builtin_amdgcn_sched_barrier(0);
  compute((NSTEP - 2) & 3, scv[(NSTEP - 2) >> 1]);

  asm volatile("s_waitcnt vmcnt(0)" ::: "memory");
  __builtin_amdgcn_s_barrier();
  __builtin_amdgcn_sched_barrier(0);
  compute((NSTEP - 1) & 3, scv[(NSTEP - 1) >> 1]);

  // ---- epilogue: direct f32 atomicAdd into out (no fence needed).
  // D row = mt*16 + 4*lg + j, col = cw + fr; 16-lane groups hit 64B lines.
  #pragma unroll
  for (int mt = 0; mt < 4; ++mt)
    #pragma unroll
    for (int j = 0; j < 4; ++j)
      atomicAdd(out + (size_t)(mt * 16 + 4 * lg + j) * N_ + n0 + cw + fr,
                acc[mt][j]);
}

// ---------------- fallback (ws too small): 2-buf, atomic epilogue ----------
__global__ __launch_bounds__(512, 8) void dq_gemm_basic(
    const int* __restrict__ q, const float* __restrict__ s,
    const float* __restrict__ Af, float* __restrict__ out) {
  __shared__ int tile[2][BK * BN];

  const int tid = threadIdx.x;
  const int l   = tid & 63;
  const int w   = tid >> 6;
  const int fr  = l & 15;
  const int lg  = l >> 4;
  const int cb  = blockIdx.x % CB;
  const int sb  = blockIdx.x / CB;
  const int n0  = cb * BN;
  const int k0  = sb * KBAND;
  const int cw  = w * 16;

  f32x4 acc[4] = {f32x4{0,0,0,0}, f32x4{0,0,0,0}, f32x4{0,0,0,0}, f32x4{0,0,0,0}};

  auto stage = [&](int buf, int kst) {
    #pragma unroll
    for (int i = 0; i < 2; ++i) {
      const int rbase = w * 4 + i * 2;
      const int row   = rbase + (l >> 5);
      const int rot   = ((row >> 3) & 3) * 8;
      const int c4    = (4 * l) & 127;
      const int src   = (c4 - rot) & 127;
      const int* gp   = q + (size_t)(kst + row) * N_ + n0 + src;
      __builtin_amdgcn_global_load_lds(
          (const __attribute__((address_space(1))) unsigned*)gp,
          (__attribute__((address_space(3))) unsigned*)&tile[buf][rbase * BN],
          16, 0, 0);
    }
  };

  auto compute = [&](int buf, int kst) {
    const float sc = s[(size_t)(kst >> 6) * N_ + n0 + cw + fr];
    bf16x8 af[4];
    #pragma unroll
    for (int mt = 0; mt < 4; ++mt) {
      const float* ap = Af + (size_t)(mt * 16 + fr) * K_ + kst + 8 * lg;
      float4v v0 = *reinterpret_cast<const float4v*>(ap);
      float4v v1 = *reinterpret_cast<const float4v*>(ap + 4);
      uint4v b = { pack_bf16(v0[0], v0[1]), pack_bf16(v0[2], v0[3]),
                   pack_bf16(v1[0], v1[1]), pack_bf16(v1[2], v1[3]) };
      af[mt] = __builtin_bit_cast(bf16x8, b);
    }
    const float sn = -4.0f * sc;
    const int rot = 8 * lg;
    const int ci  = (cw + fr + rot) & 127;
    unsigned pk[4];
    #pragma unroll
    for (int p = 0; p < 4; ++p) {
      const int r0 = 8 * lg + 2 * p;
      const int c0 = tile[buf][r0 * BN + ci];
      const int c1 = tile[buf][(r0 + 1) * BN + ci];
      pk[p] = pack_bf16(fmaf((float)c0, sc, sn), fmaf((float)c1, sc, sn));
    }
    uint4v bv = {pk[0], pk[1], pk[2], pk[3]};
    const bf16x8 bfrag = __builtin_bit_cast(bf16x8, bv);
    #pragma unroll
    for (int mt = 0; mt < 4; ++mt)
      acc[mt] = __builtin_amdgcn_mfma_f32_16x16x32_bf16(af[mt], bfrag, acc[mt],
                                                        0, 0, 0);
  };

  stage(0, k0);
  __syncthreads();
  for (int st = 0; st < NSTEP; ++st) {
    const int kst = k0 + st * BK;
    if (st + 1 < NSTEP) stage((st + 1) & 1, kst + BK);
    compute(st & 1, kst);
    __syncthreads();
  }

  #pragma unroll
  for (int mt = 0; mt < 4; ++mt)
    #pragma unroll
    for (int j = 0; j < 4; ++j)
      atomicAdd(out + (size_t)(mt * 16 + 4 * lg + j) * N_ + n0 + cw + fr,
                acc[mt][j]);
}

extern "C" void kernel_launch(void* const* d_in, const int* in_sizes, int n_in,
                              void* d_out, int out_size, void* d_ws, size_t ws_size,
                              hipStream_t stream) {
  const float* A = (const float*)d_in[0];
  const int*   q = (const int*)d_in[1];
  const float* s = (const float*)d_in[2];
  float* out = (float*)d_out;

  const size_t apBytes = (size_t)128 * 1024 * sizeof(unsigned);      // 512 KB

  hipMemsetAsync(d_out, 0, (size_t)M_ * N_ * sizeof(float), stream);
  if (ws_size >= apBytes) {
    unsigned* Apf = (unsigned*)d_ws;
    hipLaunchKernelGGL(cvtA_frag_kernel, dim3(128), dim3(256), 0, stream,
                       A, Apf);
    hipLaunchKernelGGL(dq_gemm_pipe, dim3(CB * SB), dim3(512), 0, stream,
                       q, s, Apf, out);
  } else {
    hipLaunchKernelGGL(dq_gemm_basic, dim3(CB * SB), dim3(512), 0, stream,
                       q, s, A, out);
  }
}

// Round 11
// 44.487 us; speedup vs baseline: 1.2376x; 1.1783x over previous
//
// Fused 3-bit dequant GEMM: C[64,11008] = A[64,4096] @ ((q-4) * s[group])
// R11: EXACT REVERT to R6 (best measured: 44.1us). R7-R10 each tested one
// alternative to the 3-dispatch chain and ALL regressed:
//   R7 fused-reduction w/ __threadfence: agent fences flush non-coherent
//      per-XCD L2s -> 420 GB/s collapse (213us).
//   R8 SB=4 + stage-early: -2us (46.1).
//   R9 cvtA folded in: 96KB LDS -> 1 blk/CU, TLP halved (55.1).
//   R10 f32 atomicAdd epilogue: 5.6M memory-side RMWs burst (52.4).
// Main kernel: 182MB at ~5.4 TB/s = ~87% of the 6.3 TB/s measured copy
// ceiling; granule-size/pipeline-depth/stage-order/occupancy experiments all
// moved it <=3% -> at the access-pattern roofline. Remaining ~9us = cvtA +
// reduce + graph gaps, shown irreducible by the R7-R10 ablation.
// Structure: NBUF=4 circular LDS pipeline, counted vmcnt(8/4/0) + raw
// s_barrier + sched_barrier(0), 4 uniform loads/stage/wave (2 q-dwordx4 +
// 2 A-frag dword), rotation swizzle (2-way bank = free), Apf fragment-order
// A (contiguous broadcast reads), bf16 partials + reduce kernel.

#include <hip/hip_runtime.h>

#define K_ 4096
#define N_ 11008
#define M_ 64
#define SB 8                    // k-split factor
#define CB 86                   // column chunks of BN
#define BK 32                   // k rows per tile
#define BN 128                  // columns per block
#define KBAND (K_ / SB)         // 512
#define NSTEP (KBAND / BK)      // 16
#define NBUF 4

typedef __attribute__((ext_vector_type(8))) short bf16x8;
typedef __attribute__((ext_vector_type(4))) float f32x4;
typedef __attribute__((ext_vector_type(4))) unsigned uint4v;
typedef __attribute__((ext_vector_type(4))) float float4v;
typedef __attribute__((ext_vector_type(4))) unsigned short ushort4v;

static __device__ __forceinline__ unsigned rne_bits(float f) {
  unsigned u = __builtin_bit_cast(unsigned, f);
  return u + 0x7fffu + ((u >> 16) & 1u);   // bf16 in bits [31:16], RNE
}
static __device__ __forceinline__ unsigned pack_bf16(float lo, float hi) {
  return (rne_bits(hi) & 0xffff0000u) | (rne_bits(lo) >> 16);
}
static __device__ __forceinline__ unsigned short bf16_1(float f) {
  return (unsigned short)(rne_bits(f) >> 16);
}
static __device__ __forceinline__ float bf16_to_f32(unsigned short u) {
  return __builtin_bit_cast(float, (unsigned)u << 16);
}

// A (64x4096 f32) -> Apf in MFMA fragment order: Apf[kt][mt][lane] = 8 bf16
// (4 uints). kt=k/32 (128), mt=row-tile (4), lane=64. 512KB total.
__global__ __launch_bounds__(256) void cvtA_frag_kernel(
    const float* __restrict__ A, unsigned* __restrict__ Apf) {
  const int kt = blockIdx.x;          // 0..127
  const int mt = threadIdx.x >> 6;    // 0..3
  const int l  = threadIdx.x & 63;
  const int row = mt * 16 + (l & 15);
  const int kk  = kt * 32 + (l >> 4) * 8;
  const float* ap = A + (size_t)row * K_ + kk;
  uint4v b = { pack_bf16(ap[0], ap[1]), pack_bf16(ap[2], ap[3]),
               pack_bf16(ap[4], ap[5]), pack_bf16(ap[6], ap[7]) };
  *reinterpret_cast<uint4v*>(Apf + ((size_t)(kt * 4 + mt) * 64 + l) * 4) = b;
}

// ---------------- pipelined hot path (requires Apf + P in d_ws) ------------
__global__ __launch_bounds__(512, 4) void dq_gemm_pipe(
    const int* __restrict__ q, const float* __restrict__ s,
    const unsigned* __restrict__ Apf, unsigned short* __restrict__ P) {
  __shared__ int qtile[NBUF][BK * BN];   // 4 x 16KB
  __shared__ int atile[NBUF][1024];      // 4 x 4KB  (Apf[kt] linear copy)

  const int tid = threadIdx.x;
  const int l   = tid & 63;
  const int w   = tid >> 6;           // wave 0..7 (owns 16 columns)
  const int fr  = l & 15;
  const int lg  = l >> 4;
  const int cb  = blockIdx.x % CB;
  const int sb  = blockIdx.x / CB;
  const int n0  = cb * BN;
  const int k0  = sb * KBAND;
  const int cw  = w * 16;

  // --- scales preload FIRST (oldest vmem; retired by the first wait) ---
  float scv[NSTEP / 2];
  #pragma unroll
  for (int g = 0; g < NSTEP / 2; ++g)
    scv[g] = s[(size_t)((k0 >> 6) + g) * N_ + n0 + cw + fr];

  f32x4 acc[4] = {f32x4{0,0,0,0}, f32x4{0,0,0,0}, f32x4{0,0,0,0}, f32x4{0,0,0,0}};

  // stage = exactly 4 uniform loads/wave: 2x q dwordx4 (rotation swizzle via
  // pre-rotated per-lane global source; LDS dest linear) + 2x A-frag dword.
  auto stage = [&](int buf, int kst) {
    #pragma unroll
    for (int i = 0; i < 2; ++i) {
      const int rbase = w * 4 + i * 2;               // wave-uniform row pair
      const int row   = rbase + (l >> 5);
      const int rot   = ((row >> 3) & 3) * 8;
      const int c4    = (4 * l) & 127;
      const int src   = (c4 - rot) & 127;
      const int* gp   = q + (size_t)(kst + row) * N_ + n0 + src;
      __builtin_amdgcn_global_load_lds(
          (const __attribute__((address_space(1))) unsigned*)gp,
          (__attribute__((address_space(3))) unsigned*)&qtile[buf][rbase * BN],
          16, 0, 0);
    }
    const unsigned* ab = Apf + (size_t)(kst >> 5) * 1024 + w * 128;
    #pragma unroll
    for (int i = 0; i < 2; ++i) {
      __builtin_amdgcn_global_load_lds(
          (const __attribute__((address_space(1))) unsigned*)(ab + i * 64 + l),
          (__attribute__((address_space(3))) unsigned*)&atile[buf][w * 128 + i * 64],
          4, 0, 0);
    }
  };

  auto compute = [&](int buf, float sc) {
    bf16x8 af[4];
    #pragma unroll
    for (int mt = 0; mt < 4; ++mt)
      af[mt] = *reinterpret_cast<const bf16x8*>(&atile[buf][mt * 256 + l * 4]);
    const float sn = -4.0f * sc;                     // fma(q, s, -4s)
    const int rot = 8 * lg;
    const int ci  = (cw + fr + rot) & 127;
    unsigned pk[4];
    #pragma unroll
    for (int p = 0; p < 4; ++p) {
      const int r0 = 8 * lg + 2 * p;
      const int c0 = qtile[buf][r0 * BN + ci];
      const int c1 = qtile[buf][(r0 + 1) * BN + ci];
      pk[p] = pack_bf16(fmaf((float)c0, sc, sn), fmaf((float)c1, sc, sn));
    }
    uint4v bv = {pk[0], pk[1], pk[2], pk[3]};
    const bf16x8 bfrag = __builtin_bit_cast(bf16x8, bv);
    #pragma unroll
    for (int mt = 0; mt < 4; ++mt)
      acc[mt] = __builtin_amdgcn_mfma_f32_16x16x32_bf16(af[mt], bfrag, acc[mt],
                                                        0, 0, 0);
  };

  // ---- prologue: 3 tiles in flight (12 loads) ----
  stage(0, k0);
  stage(1, k0 + BK);
  stage(2, k0 + 2 * BK);

  // ---- steady state: counted wait keeps >=2 tiles in flight ----
  #pragma unroll
  for (int st = 0; st < NSTEP - 2; ++st) {
    asm volatile("s_waitcnt vmcnt(8)" ::: "memory");
    __builtin_amdgcn_s_barrier();
    __builtin_amdgcn_sched_barrier(0);   // pin ds_reads below the barrier
    compute(st & 3, scv[st >> 1]);
    if (st + 3 < NSTEP) stage((st + 3) & 3, k0 + (st + 3) * BK);
  }
  // ---- tail: two peeled steps ----
  asm volatile("s_waitcnt vmcnt(4)" ::: "memory");
  __builtin_amdgcn_s_barrier();
  __builtin_amdgcn_sched_barrier(0);
  compute((NSTEP - 2) & 3, scv[(NSTEP - 2) >> 1]);

  asm volatile("s_waitcnt vmcnt(0)" ::: "memory");
  __builtin_amdgcn_s_barrier();
  __builtin_amdgcn_sched_barrier(0);
  compute((NSTEP - 1) & 3, scv[(NSTEP - 1) >> 1]);

  // ---- epilogue: D row = mt*16 + 4*lg + j, col = cw + fr ----
  unsigned short* Pb = P + (size_t)(cb * SB + sb) * M_ * BN;
  #pragma unroll
  for (int mt = 0; mt < 4; ++mt)
    #pragma unroll
    for (int j = 0; j < 4; ++j)
      Pb[(mt * 16 + 4 * lg + j) * BN + cw + fr] = bf16_1(acc[mt][j]);
}

// Sum SB bf16 partials -> f32 out. 688 blocks x 256 thr, 1 ushort4/thread.
__global__ __launch_bounds__(256) void reduce_kernel(
    const unsigned short* __restrict__ P, float* __restrict__ out) {
  const int flat = blockIdx.x * 256 + threadIdx.x;  // 0 .. 176127
  const int cb = flat >> 11;                        // / 2048
  const int r  = flat & 2047;
  const int m  = r >> 5;                            // row (BN/4 = 32 grp/row)
  const int cq = (r & 31) * 4;
  const unsigned short* p = P + ((size_t)cb * SB * M_ + m) * BN + cq;
  float s0 = 0.f, s1 = 0.f, s2 = 0.f, s3 = 0.f;
  #pragma unroll
  for (int sb = 0; sb < SB; ++sb) {
    ushort4v v = *reinterpret_cast<const ushort4v*>(p + (size_t)sb * M_ * BN);
    s0 += bf16_to_f32(v[0]);
    s1 += bf16_to_f32(v[1]);
    s2 += bf16_to_f32(v[2]);
    s3 += bf16_to_f32(v[3]);
  }
  float4v o = {s0, s1, s2, s3};
  *reinterpret_cast<float4v*>(out + (size_t)m * N_ + cb * BN + cq) = o;
}

// ---------------- fallback (ws too small): 2-buf, atomic epilogue ----------
__global__ __launch_bounds__(512, 8) void dq_gemm_basic(
    const int* __restrict__ q, const float* __restrict__ s,
    const float* __restrict__ Af, float* __restrict__ out) {
  __shared__ int tile[2][BK * BN];

  const int tid = threadIdx.x;
  const int l   = tid & 63;
  const int w   = tid >> 6;
  const int fr  = l & 15;
  const int lg  = l >> 4;
  const int cb  = blockIdx.x % CB;
  const int sb  = blockIdx.x / CB;
  const int n0  = cb * BN;
  const int k0  = sb * KBAND;
  const int cw  = w * 16;

  f32x4 acc[4] = {f32x4{0,0,0,0}, f32x4{0,0,0,0}, f32x4{0,0,0,0}, f32x4{0,0,0,0}};

  auto stage = [&](int buf, int kst) {
    #pragma unroll
    for (int i = 0; i < 2; ++i) {
      const int rbase = w * 4 + i * 2;
      const int row   = rbase + (l >> 5);
      const int rot   = ((row >> 3) & 3) * 8;
      const int c4    = (4 * l) & 127;
      const int src   = (c4 - rot) & 127;
      const int* gp   = q + (size_t)(kst + row) * N_ + n0 + src;
      __builtin_amdgcn_global_load_lds(
          (const __attribute__((address_space(1))) unsigned*)gp,
          (__attribute__((address_space(3))) unsigned*)&tile[buf][rbase * BN],
          16, 0, 0);
    }
  };

  auto compute = [&](int buf, int kst) {
    const float sc = s[(size_t)(kst >> 6) * N_ + n0 + cw + fr];
    bf16x8 af[4];
    #pragma unroll
    for (int mt = 0; mt < 4; ++mt) {
      const float* ap = Af + (size_t)(mt * 16 + fr) * K_ + kst + 8 * lg;
      float4v v0 = *reinterpret_cast<const float4v*>(ap);
      float4v v1 = *reinterpret_cast<const float4v*>(ap + 4);
      uint4v b = { pack_bf16(v0[0], v0[1]), pack_bf16(v0[2], v0[3]),
                   pack_bf16(v1[0], v1[1]), pack_bf16(v1[2], v1[3]) };
      af[mt] = __builtin_bit_cast(bf16x8, b);
    }
    const float sn = -4.0f * sc;
    const int rot = 8 * lg;
    const int ci  = (cw + fr + rot) & 127;
    unsigned pk[4];
    #pragma unroll
    for (int p = 0; p < 4; ++p) {
      const int r0 = 8 * lg + 2 * p;
      const int c0 = tile[buf][r0 * BN + ci];
      const int c1 = tile[buf][(r0 + 1) * BN + ci];
      pk[p] = pack_bf16(fmaf((float)c0, sc, sn), fmaf((float)c1, sc, sn));
    }
    uint4v bv = {pk[0], pk[1], pk[2], pk[3]};
    const bf16x8 bfrag = __builtin_bit_cast(bf16x8, bv);
    #pragma unroll
    for (int mt = 0; mt < 4; ++mt)
      acc[mt] = __builtin_amdgcn_mfma_f32_16x16x32_bf16(af[mt], bfrag, acc[mt],
                                                        0, 0, 0);
  };

  stage(0, k0);
  __syncthreads();
  for (int st = 0; st < NSTEP; ++st) {
    const int kst = k0 + st * BK;
    if (st + 1 < NSTEP) stage((st + 1) & 1, kst + BK);
    compute(st & 1, kst);
    __syncthreads();
  }

  #pragma unroll
  for (int mt = 0; mt < 4; ++mt)
    #pragma unroll
    for (int j = 0; j < 4; ++j)
      atomicAdd(out + (size_t)(mt * 16 + 4 * lg + j) * N_ + n0 + cw + fr,
                acc[mt][j]);
}

extern "C" void kernel_launch(void* const* d_in, const int* in_sizes, int n_in,
                              void* d_out, int out_size, void* d_ws, size_t ws_size,
                              hipStream_t stream) {
  const float* A = (const float*)d_in[0];
  const int*   q = (const int*)d_in[1];
  const float* s = (const float*)d_in[2];
  float* out = (float*)d_out;

  const size_t apBytes = (size_t)128 * 1024 * sizeof(unsigned);      // 512 KB
  const size_t pBytes  = (size_t)CB * SB * M_ * BN * sizeof(unsigned short);
  const size_t needFull = apBytes + pBytes;                          // ~11.8 MB

  if (ws_size >= needFull) {
    unsigned* Apf = (unsigned*)d_ws;
    unsigned short* P = (unsigned short*)((char*)d_ws + apBytes);
    hipLaunchKernelGGL(cvtA_frag_kernel, dim3(128), dim3(256), 0, stream,
                       A, Apf);
    hipLaunchKernelGGL(dq_gemm_pipe, dim3(CB * SB), dim3(512), 0, stream,
                       q, s, Apf, P);
    hipLaunchKernelGGL(reduce_kernel, dim3(688), dim3(256), 0, stream, P, out);
  } else {
    hipMemsetAsync(d_out, 0, (size_t)M_ * N_ * sizeof(float), stream);
    hipLaunchKernelGGL(dq_gemm_basic, dim3(CB * SB), dim3(512), 0, stream,
                       q, s, A, out);
  }
}